// Round 13
// baseline (755.537 us; speedup 1.0000x reference)
//
#include <hip/hip_runtime.h>
#include <math.h>

// ---------------- constants ----------------
#define B_   64
#define S_   256
#define D_   256
#define H_   8
#define DH_  32
#define FF_  1024
#define MEM_ 200000
#define ROWS_ (B_ * S_)   // 16384
#define NCHB_ 1563        // sims blocks per row = chunk-max slots (ceil(MEM/128))
#define CAP_  2048        // candidate cap per row

typedef float f32x4 __attribute__((ext_vector_type(4)));
typedef __bf16 bf16x8 __attribute__((ext_vector_type(8)));
typedef unsigned short ushort_t;
typedef unsigned long long u64_t;

// ---------------- helpers ----------------
__device__ __forceinline__ float blockReduceSum256(float v, float* sh) {
  #pragma unroll
  for (int o = 32; o; o >>= 1) v += __shfl_down(v, o);
  int lane = threadIdx.x & 63, w = threadIdx.x >> 6;
  __syncthreads();
  if (lane == 0) sh[w] = v;
  __syncthreads();
  return sh[0] + sh[1] + sh[2] + sh[3];
}

__device__ __forceinline__ unsigned int f2key(float f) {
  unsigned int b = __float_as_uint(f);
  return (b & 0x80000000u) ? ~b : (b | 0x80000000u);
}
__device__ __forceinline__ float key2f(unsigned int u) {
  unsigned int b = (u & 0x80000000u) ? (u & 0x7FFFFFFFu) : ~u;
  return __uint_as_float(b);
}
__device__ __forceinline__ u64_t ullmax(u64_t a, u64_t b) { return a > b ? a : b; }

__device__ __forceinline__ ushort_t f32_bf16_rn(float x) {
  unsigned int u = __float_as_uint(x);
  u += 0x7FFFu + ((u >> 16) & 1u);
  return (ushort_t)(u >> 16);
}
__device__ __forceinline__ float bf16_f32(ushort_t h) {
  return __uint_as_float((unsigned int)h << 16);
}
__device__ __forceinline__ void split_bf16(float v, ushort_t& h, ushort_t& l) {
  h = f32_bf16_rn(v);
  l = f32_bf16_rn(v - bf16_f32(h));
}

// swizzled byte offset into a [R][32] bf16 LDS tile (16B granules, granule ^= (row>>1)&3)
__device__ __forceinline__ int swz16(int row, int kg) {
  return row * 64 + (((kg ^ ((row >> 1) & 3)) << 4));
}

// direct global->LDS 16B copy
__device__ __forceinline__ void gload_lds16(const void* gsrc, void* ldst) {
  __builtin_amdgcn_global_load_lds(
      (const __attribute__((address_space(1))) unsigned int*)gsrc,
      (__attribute__((address_space(3))) unsigned int*)(unsigned int)(unsigned long long)ldst,
      16, 0, 0);
}

// stage a [NIT*64 x 32] bf16 tile from linear global into swizzled LDS (pre-swizzled source)
template<int NIT>
__device__ __forceinline__ void stage16(const ushort_t* __restrict__ G, int ldg,
                                        int base_row, int k0, char* lds, int t) {
  #pragma unroll
  for (int r = 0; r < NIT; ++r) {
    int idx = r * 256 + t;
    int row = idx >> 2, kg = idx & 3;
    int kg_g = kg ^ ((row >> 1) & 3);
    const void* src = G + (size_t)(base_row + row) * ldg + k0 + kg_g * 8;
    void* dst = lds + (size_t)(idx & ~63) * 16;
    gload_lds16(src, dst);
  }
}

// ---------------- bf16x3 MFMA GEMM on pre-split hi/lo inputs (round-8 form, all-LDS) ----------------
template<int ACT, bool HAS_BIAS, int OUTMODE>
__global__ __launch_bounds__(256) void gemm16(const ushort_t* __restrict__ AH,
                                              const ushort_t* __restrict__ AL,
                                              const ushort_t* __restrict__ BH,
                                              const ushort_t* __restrict__ BL,
                                              const float* __restrict__ bias,
                                              float* __restrict__ C,
                                              ushort_t* __restrict__ CH,
                                              ushort_t* __restrict__ CL,
                                              int M, int N, int K) {
  __shared__ __align__(16) char sAh[128 * 64];
  __shared__ __align__(16) char sAl[128 * 64];
  __shared__ __align__(16) char sBh[128 * 64];
  __shared__ __align__(16) char sBl[128 * 64];
  int t = threadIdx.x;
  int m0 = blockIdx.y * 128, n0 = blockIdx.x * 128;
  int wid = t >> 6, lane = t & 63;
  int wr = wid >> 1, wc = wid & 1;
  int lr = lane & 15, kg = lane >> 4;
  f32x4 acc[4][4] = {};
  for (int k0 = 0; k0 < K; k0 += 32) {
    stage16<2>(AH, K, m0, k0, sAh, t);
    stage16<2>(AL, K, m0, k0, sAl, t);
    stage16<2>(BH, K, n0, k0, sBh, t);
    stage16<2>(BL, K, n0, k0, sBl, t);
    __syncthreads();
    bf16x8 ah[4], al[4];
    #pragma unroll
    for (int mi = 0; mi < 4; ++mi) {
      int row = wr * 64 + mi * 16 + lr;
      int ab = swz16(row, kg);
      ah[mi] = *reinterpret_cast<const bf16x8*>(sAh + ab);
      al[mi] = *reinterpret_cast<const bf16x8*>(sAl + ab);
    }
    #pragma unroll
    for (int ni = 0; ni < 4; ++ni) {
      int rb = wc * 64 + ni * 16 + lr;
      int bb = swz16(rb, kg);
      bf16x8 bh = *reinterpret_cast<const bf16x8*>(sBh + bb);
      bf16x8 bl = *reinterpret_cast<const bf16x8*>(sBl + bb);
      #pragma unroll
      for (int mi = 0; mi < 4; ++mi) {
        acc[mi][ni] = __builtin_amdgcn_mfma_f32_16x16x32_bf16(ah[mi], bh, acc[mi][ni], 0, 0, 0);
        acc[mi][ni] = __builtin_amdgcn_mfma_f32_16x16x32_bf16(al[mi], bh, acc[mi][ni], 0, 0, 0);
        acc[mi][ni] = __builtin_amdgcn_mfma_f32_16x16x32_bf16(ah[mi], bl, acc[mi][ni], 0, 0, 0);
      }
    }
    __syncthreads();
  }
  #pragma unroll
  for (int mi = 0; mi < 4; ++mi) {
    #pragma unroll
    for (int ni = 0; ni < 4; ++ni) {
      int row0 = m0 + wr * 64 + mi * 16 + kg * 4;
      int col  = n0 + wc * 64 + ni * 16 + lr;
      float b = HAS_BIAS ? bias[col] : 0.0f;
      #pragma unroll
      for (int i = 0; i < 4; ++i) {
        float v = acc[mi][ni][i] + b;
        if (ACT == 1) v = 0.5f * v * (1.0f + erff(v * 0.7071067811865476f));
        size_t o = (size_t)(row0 + i) * N + col;
        if (OUTMODE == 0) {
          C[o] = v;
        } else {
          ushort_t h, l;
          split_bf16(v, h, l);
          CH[o] = h; CL[o] = l;
        }
      }
    }
  }
}

// ---------------- sims GEMM v5: zero-barrier K-loop + 1-deep B prefetch ----------------
// Same math/order as v3 (bit-identical); only the load ISSUE order changes so step k+1's
// four HBM float4 loads are in flight while step k converts + MFMAs.
#define SIMS_STEP(BA, BB, SS, NI)                                                          \
  {                                                                                        \
    float q[8] = {BA.x, BA.y, BA.z, BA.w, BB.x, BB.y, BB.z, BB.w};                         \
    union { bf16x8 v; ushort_t u[8]; } bh, bl;                                             \
    float s_ = 0.f;                                                                        \
    _Pragma("unroll")                                                                      \
    for (int j = 0; j < 8; ++j) {                                                          \
      split_bf16(q[j], bh.u[j], bl.u[j]);                                                  \
      s_ += q[j] * q[j];                                                                   \
    }                                                                                      \
    SS += s_;                                                                              \
    _Pragma("unroll")                                                                      \
    for (int mi = 0; mi < 4; ++mi) {                                                       \
      acc[mi][NI] = __builtin_amdgcn_mfma_f32_16x16x32_bf16(ah[mi], bh.v, acc[mi][NI], 0, 0, 0); \
      acc[mi][NI] = __builtin_amdgcn_mfma_f32_16x16x32_bf16(al[mi], bh.v, acc[mi][NI], 0, 0, 0); \
      acc[mi][NI] = __builtin_amdgcn_mfma_f32_16x16x32_bf16(ah[mi], bl.v, acc[mi][NI], 0, 0, 0); \
    }                                                                                      \
  }

__global__ __launch_bounds__(256) void sims_gemm(const ushort_t* __restrict__ QNH,
                                                 const ushort_t* __restrict__ QNL,
                                                 const float* __restrict__ keys,
                                                 float* __restrict__ sims,
                                                 u64_t* __restrict__ chm) {
  __shared__ u64_t wmax[4][64];
  int t = threadIdx.x;
  int n0 = blockIdx.x * 128;
  int w = t >> 6, lane = t & 63;
  int lr = lane & 15, kg = lane >> 4;
  int col0 = n0 + w * 32 + lr;
  int col1 = col0 + 16;
  int c0 = col0 < MEM_ ? col0 : MEM_ - 1;
  int c1 = col1 < MEM_ ? col1 : MEM_ - 1;
  const float* kp0 = keys + (size_t)c0 * 256 + kg * 8;
  const float* kp1 = keys + (size_t)c1 * 256 + kg * 8;
  float ss0 = 0.f, ss1 = 0.f;
  f32x4 acc[4][2] = {};
  // prologue: first B tile in flight
  float4 b0a = *reinterpret_cast<const float4*>(kp0);
  float4 b0b = *reinterpret_cast<const float4*>(kp0 + 4);
  float4 b1a = *reinterpret_cast<const float4*>(kp1);
  float4 b1b = *reinterpret_cast<const float4*>(kp1 + 4);
  #pragma unroll
  for (int ks = 0; ks < 8; ++ks) {
    int k0 = ks * 32;
    // issue NEXT step's B loads before using the current registers
    float4 n0a, n0b, n1a, n1b;
    if (ks < 7) {
      n0a = *reinterpret_cast<const float4*>(kp0 + k0 + 32);
      n0b = *reinterpret_cast<const float4*>(kp0 + k0 + 36);
      n1a = *reinterpret_cast<const float4*>(kp1 + k0 + 32);
      n1b = *reinterpret_cast<const float4*>(kp1 + k0 + 36);
    }
    // A frags (L2-resident QN pairs)
    bf16x8 ah[4], al[4];
    #pragma unroll
    for (int mi = 0; mi < 4; ++mi) {
      size_t ao = (size_t)(mi * 16 + lr) * 256 + k0 + kg * 8;
      ah[mi] = *reinterpret_cast<const bf16x8*>(QNH + ao);
      al[mi] = *reinterpret_cast<const bf16x8*>(QNL + ao);
    }
    SIMS_STEP(b0a, b0b, ss0, 0)
    SIMS_STEP(b1a, b1b, ss1, 1)
    if (ks < 7) { b0a = n0a; b0b = n0b; b1a = n1a; b1b = n1b; }
  }
  float invn[2];
  {
    float s0 = ss0, s1 = ss1;
    s0 += __shfl_xor(s0, 16); s0 += __shfl_xor(s0, 32);
    s1 += __shfl_xor(s1, 16); s1 += __shfl_xor(s1, 32);
    invn[0] = 1.0f / fmaxf(sqrtf(s0), 1e-8f);
    invn[1] = 1.0f / fmaxf(sqrtf(s1), 1e-8f);
  }
  u64_t bq[4][4];
  #pragma unroll
  for (int mi = 0; mi < 4; ++mi)
    #pragma unroll
    for (int i = 0; i < 4; ++i) bq[mi][i] = 0ull;
  #pragma unroll
  for (int ni = 0; ni < 2; ++ni) {
    int col = ni ? col1 : col0;
    if (col < MEM_) {
      #pragma unroll
      for (int mi = 0; mi < 4; ++mi) {
        int q = mi * 16 + kg * 4;
        #pragma unroll
        for (int i = 0; i < 4; ++i) {
          float v = acc[mi][ni][i] * invn[ni];
          sims[(size_t)(q + i) * MEM_ + col] = v;
          u64_t key = ((u64_t)f2key(v) << 32) | (unsigned int)~(unsigned int)col;
          bq[mi][i] = ullmax(bq[mi][i], key);
        }
      }
    }
  }
  #pragma unroll
  for (int mi = 0; mi < 4; ++mi)
    #pragma unroll
    for (int i = 0; i < 4; ++i) {
      u64_t m = bq[mi][i];
      m = ullmax(m, __shfl_xor(m, 1));
      m = ullmax(m, __shfl_xor(m, 2));
      m = ullmax(m, __shfl_xor(m, 4));
      m = ullmax(m, __shfl_xor(m, 8));
      if (lr == 0) wmax[w][mi * 16 + kg * 4 + i] = m;
    }
  __syncthreads();
  if (t < 64) {
    u64_t m = ullmax(ullmax(wmax[0][t], wmax[1][t]), ullmax(wmax[2][t], wmax[3][t]));
    chm[(size_t)t * NCHB_ + blockIdx.x] = m;
  }
}

// ---------------- all weight transposes + bf16 hi/lo split in ONE launch ----------------
__global__ __launch_bounds__(256) void transcvt_all(const float* __restrict__ qkv_w,
                                                    const float* __restrict__ out_w,
                                                    const float* __restrict__ ff_w1,
                                                    const float* __restrict__ ff_w2,
                                                    ushort_t* __restrict__ WP) {
  __shared__ float tile[32][33];
  int idx = blockIdx.x;
  int l = idx / 768, r = idx % 768;
  const float* src; ushort_t *dh, *dl; int R, C, bx, by;
  ushort_t* base = WP + (size_t)l * 1572864;
  if (r < 192)      { src = qkv_w + (size_t)l * 196608; dh = base;           dl = base + 196608;  R = 256;  C = 768;  bx = r % 24;        by = r / 24; }
  else if (r < 256) { src = out_w + (size_t)l * 65536;  dh = base + 393216;  dl = base + 458752;  R = 256;  C = 256;  bx = (r - 192) % 8; by = (r - 192) / 8; }
  else if (r < 512) { src = ff_w1 + (size_t)l * 262144; dh = base + 524288;  dl = base + 786432;  R = 256;  C = 1024; bx = (r - 256) % 32; by = (r - 256) / 32; }
  else              { src = ff_w2 + (size_t)l * 262144; dh = base + 1048576; dl = base + 1310720; R = 1024; C = 256;  bx = (r - 512) % 8; by = (r - 512) / 8; }
  int c0 = bx * 32, r0 = by * 32;
  int x = threadIdx.x & 31, y4 = (threadIdx.x >> 5) * 4;
  #pragma unroll
  for (int i = 0; i < 4; ++i) tile[y4 + i][x] = src[(size_t)(r0 + y4 + i) * C + c0 + x];
  __syncthreads();
  #pragma unroll
  for (int i = 0; i < 4; ++i) {
    float v = tile[x][y4 + i];
    ushort_t h, l2;
    split_bf16(v, h, l2);
    size_t o = (size_t)(c0 + y4 + i) * R + r0 + x;
    dh[o] = h; dl[o] = l2;
  }
}

// ---------------- embedding + positional encoding ----------------
__global__ __launch_bounds__(256) void embed_kernel(const int* __restrict__ ids,
                                                    const float* __restrict__ emb,
                                                    float* __restrict__ x,
                                                    ushort_t* __restrict__ xh,
                                                    ushort_t* __restrict__ xl) {
  int row = blockIdx.x;
  int d = threadIdx.x;
  int s = row & (S_ - 1);
  int tok = ids[row];
  int d2 = d & ~1;
  float div = expf((float)d2 * (-9.210340371976184f / 256.0f));
  float ang = (float)s * div;
  float pe = (d & 1) ? cosf(ang) : sinf(ang);
  float v = emb[(size_t)tok * D_ + d] * 16.0f + pe;
  size_t o = (size_t)row * D_ + d;
  x[o] = v;
  ushort_t h, l;
  split_bf16(v, h, l);
  xh[o] = h; xl[o] = l;
}

// ---------------- MFMA flash attention (round-8 form: f32 QKV in, LDS staging) ----------------
__global__ __launch_bounds__(256) void attn_kernel(const float* __restrict__ qkv,
                                                   ushort_t* __restrict__ ctxh,
                                                   ushort_t* __restrict__ ctxl) {
  __shared__ __align__(16) ushort_t sKh[32][40];
  __shared__ __align__(16) ushort_t sKl[32][40];
  __shared__ __align__(16) ushort_t sVh[32][40];
  __shared__ __align__(16) ushort_t sVl[32][40];
  __shared__ __align__(16) ushort_t sPh[4][64][40];
  __shared__ __align__(16) ushort_t sPl[4][64][40];

  const int bh = blockIdx.x;
  const int b = bh >> 3, h = bh & 7;
  const int t = threadIdx.x;
  const int w = t >> 6, lane = t & 63;
  const int lr = lane & 15, g = lane >> 4;

  const float* __restrict__ base = qkv + (size_t)(b * S_) * 768 + h * 32;

  bf16x8 qh[4], ql[4];
  #pragma unroll
  for (int ni = 0; ni < 4; ++ni) {
    const float* qp = base + (size_t)(w * 64 + ni * 16 + lr) * 768 + g * 8;
    union { bf16x8 v; ushort_t u[8]; } Hh, Ll;
    #pragma unroll
    for (int j = 0; j < 8; ++j) {
      float qv = qp[j] * 0.17677669529663687f;
      split_bf16(qv, Hh.u[j], Ll.u[j]);
    }
    qh[ni] = Hh.v; ql[ni] = Ll.v;
  }

  f32x4 oacc[2][4] = {};
  float mrow[4] = {-3.0e38f, -3.0e38f, -3.0e38f, -3.0e38f};
  float lsum[4] = {0.f, 0.f, 0.f, 0.f};

  for (int kt = 0; kt < 8; ++kt) {
    __syncthreads();
    {
      int key = t >> 3, c4 = t & 7;
      const float4 kv = *reinterpret_cast<const float4*>(
          base + (size_t)(kt * 32 + key) * 768 + 256 + c4 * 4);
      float kvv[4] = {kv.x, kv.y, kv.z, kv.w};
      ushort_t hk[4], lk[4];
      #pragma unroll
      for (int j = 0; j < 4; ++j) split_bf16(kvv[j], hk[j], lk[j]);
      *reinterpret_cast<uint2*>(&sKh[key][c4 * 4]) =
          make_uint2((unsigned)hk[0] | ((unsigned)hk[1] << 16),
                     (unsigned)hk[2] | ((unsigned)hk[3] << 16));
      *reinterpret_cast<uint2*>(&sKl[key][c4 * 4]) =
          make_uint2((unsigned)lk[0] | ((unsigned)lk[1] << 16),
                     (unsigned)lk[2] | ((unsigned)lk[3] << 16));
      int dh = t & 31, kq = t >> 5;
      ushort_t hv[4], lv[4];
      #pragma unroll
      for (int kk = 0; kk < 4; ++kk) {
        float vv = base[(size_t)(kt * 32 + kq * 4 + kk) * 768 + 512 + dh];
        split_bf16(vv, hv[kk], lv[kk]);
      }
      *reinterpret_cast<uint2*>(&sVh[dh][kq * 4]) =
          make_uint2((unsigned)hv[0] | ((unsigned)hv[1] << 16),
                     (unsigned)hv[2] | ((unsigned)hv[3] << 16));
      *reinterpret_cast<uint2*>(&sVl[dh][kq * 4]) =
          make_uint2((unsigned)lv[0] | ((unsigned)lv[1] << 16),
                     (unsigned)lv[2] | ((unsigned)lv[3] << 16));
    }
    __syncthreads();

    f32x4 sacc[2][4] = {};
    bf16x8 kfh[2], kfl[2];
    #pragma unroll
    for (int x = 0; x < 2; ++x) {
      kfh[x] = *reinterpret_cast<const bf16x8*>(&sKh[x * 16 + lr][g * 8]);
      kfl[x] = *reinterpret_cast<const bf16x8*>(&sKl[x * 16 + lr][g * 8]);
    }
    #pragma unroll
    for (int x = 0; x < 2; ++x) {
      #pragma unroll
      for (int ni = 0; ni < 4; ++ni) {
        sacc[x][ni] = __builtin_amdgcn_mfma_f32_16x16x32_bf16(kfh[x], qh[ni], sacc[x][ni], 0, 0, 0);
        sacc[x][ni] = __builtin_amdgcn_mfma_f32_16x16x32_bf16(kfl[x], qh[ni], sacc[x][ni], 0, 0, 0);
        sacc[x][ni] = __builtin_amdgcn_mfma_f32_16x16x32_bf16(kfh[x], ql[ni], sacc[x][ni], 0, 0, 0);
      }
    }

    #pragma unroll
    for (int ni = 0; ni < 4; ++ni) {
      float tm = sacc[0][ni][0];
      tm = fmaxf(tm, sacc[0][ni][1]); tm = fmaxf(tm, sacc[0][ni][2]); tm = fmaxf(tm, sacc[0][ni][3]);
      tm = fmaxf(tm, sacc[1][ni][0]); tm = fmaxf(tm, sacc[1][ni][1]);
      tm = fmaxf(tm, sacc[1][ni][2]); tm = fmaxf(tm, sacc[1][ni][3]);
      tm = fmaxf(tm, __shfl_xor(tm, 16));
      tm = fmaxf(tm, __shfl_xor(tm, 32));
      float mn = fmaxf(mrow[ni], tm);
      float sc = __expf(mrow[ni] - mn);
      mrow[ni] = mn;
      float ps = 0.f;
      #pragma unroll
      for (int x = 0; x < 2; ++x) {
        ushort_t ph[4], pl[4];
        #pragma unroll
        for (int i = 0; i < 4; ++i) {
          float p = __expf(sacc[x][ni][i] - mn);
          ps += p;
          split_bf16(p, ph[i], pl[i]);
        }
        *reinterpret_cast<uint2*>(&sPh[w][ni * 16 + lr][x * 16 + g * 4]) =
            make_uint2((unsigned)ph[0] | ((unsigned)ph[1] << 16),
                       (unsigned)ph[2] | ((unsigned)ph[3] << 16));
        *reinterpret_cast<uint2*>(&sPl[w][ni * 16 + lr][x * 16 + g * 4]) =
            make_uint2((unsigned)pl[0] | ((unsigned)pl[1] << 16),
                       (unsigned)pl[2] | ((unsigned)pl[3] << 16));
      }
      ps += __shfl_xor(ps, 16);
      ps += __shfl_xor(ps, 32);
      lsum[ni] = lsum[ni] * sc + ps;
      #pragma unroll
      for (int mt = 0; mt < 2; ++mt)
        #pragma unroll
        for (int i = 0; i < 4; ++i) oacc[mt][ni][i] *= sc;
    }

    bf16x8 pbh[4], pbl[4];
    #pragma unroll
    for (int ni = 0; ni < 4; ++ni) {
      pbh[ni] = *reinterpret_cast<const bf16x8*>(&sPh[w][ni * 16 + lr][g * 8]);
      pbl[ni] = *reinterpret_cast<const bf16x8*>(&sPl[w][ni * 16 + lr][g * 8]);
    }
    #pragma unroll
    for (int mt = 0; mt < 2; ++mt) {
      bf16x8 vfh = *reinterpret_cast<const bf16x8*>(&sVh[mt * 16 + lr][g * 8]);
      bf16x8 vfl = *reinterpret_cast<const bf16x8*>(&sVl[mt * 16 + lr][g * 8]);
      #pragma unroll
      for (int ni = 0; ni < 4; ++ni) {
        oacc[mt][ni] = __builtin_amdgcn_mfma_f32_16x16x32_bf16(vfh, pbh[ni], oacc[mt][ni], 0, 0, 0);
        oacc[mt][ni] = __builtin_amdgcn_mfma_f32_16x16x32_bf16(vfl, pbh[ni], oacc[mt][ni], 0, 0, 0);
        oacc[mt][ni] = __builtin_amdgcn_mfma_f32_16x16x32_bf16(vfh, pbl[ni], oacc[mt][ni], 0, 0, 0);
      }
    }
  }

  #pragma unroll
  for (int ni = 0; ni < 4; ++ni) {
    float inv = 1.0f / lsum[ni];
    int q = w * 64 + ni * 16 + lr;
    size_t rowo = (size_t)(b * S_ + q) * D_ + h * 32;
    #pragma unroll
    for (int mt = 0; mt < 2; ++mt) {
      ushort_t hh[4], ll[4];
      #pragma unroll
      for (int i = 0; i < 4; ++i) {
        float v = oacc[mt][ni][i] * inv;
        split_bf16(v, hh[i], ll[i]);
      }
      int col = mt * 16 + g * 4;
      *reinterpret_cast<uint2*>(&ctxh[rowo + col]) =
          make_uint2((unsigned)hh[0] | ((unsigned)hh[1] << 16),
                     (unsigned)hh[2] | ((unsigned)hh[3] << 16));
      *reinterpret_cast<uint2*>(&ctxl[rowo + col]) =
          make_uint2((unsigned)ll[0] | ((unsigned)ll[1] << 16),
                     (unsigned)ll[2] | ((unsigned)ll[3] << 16));
    }
  }
}

// ---------------- residual add + layernorm ----------------
template<bool PAIRS>
__global__ __launch_bounds__(256) void addln_kernel(const float* __restrict__ x,
                                                    const float* __restrict__ y,
                                                    const float* __restrict__ gam,
                                                    const float* __restrict__ bet,
                                                    float* __restrict__ out,
                                                    ushort_t* __restrict__ oh,
                                                    ushort_t* __restrict__ ol) {
  __shared__ float sh[8];
  int row = blockIdx.x, d = threadIdx.x;
  float v = x[(size_t)row * D_ + d];
  if (y) v += y[(size_t)row * D_ + d];
  float mean = blockReduceSum256(v, sh) * (1.0f / D_);
  float diff = v - mean;
  float var = blockReduceSum256(diff * diff, sh) * (1.0f / D_);
  float r = diff * rsqrtf(var + 1e-5f) * gam[d] + bet[d];
  size_t o = (size_t)row * D_ + d;
  out[o] = r;
  if (PAIRS) {
    ushort_t h, l;
    split_bf16(r, h, l);
    oh[o] = h; ol[o] = l;
  }
}

// ---------------- masked mean pool + query normalize (fused; bf16-pair qn out) ----------------
__global__ __launch_bounds__(256) void pooledqnorm_kernel(const float* __restrict__ hidden,
                                                          const float* __restrict__ mask,
                                                          float* __restrict__ pooled,
                                                          ushort_t* __restrict__ qnh,
                                                          ushort_t* __restrict__ qnl) {
  __shared__ float sh[8];
  int b = blockIdx.x, d = threadIdx.x;
  float s = 0.0f, msum = 0.0f;
  for (int t = 0; t < S_; ++t) {
    float mk = mask[b * S_ + t];
    s += hidden[(size_t)(b * S_ + t) * D_ + d] * mk;
    msum += mk;
  }
  float pv = s / (msum + 1e-8f);
  pooled[b * D_ + d] = pv;
  float ss = blockReduceSum256(pv * pv, sh);
  float qv = pv / fmaxf(sqrtf(ss), 1e-8f);
  ushort_t h, l;
  split_bf16(qv, h, l);
  qnh[b * D_ + d] = h;
  qnl[b * D_ + d] = l;
}

// ---------------- tau: k-th largest of 1563 chunk maxima per row ----------------
__global__ __launch_bounds__(256) void tau_kernel(const u64_t* __restrict__ chm,
                                                  const int* __restrict__ topk,
                                                  u64_t* __restrict__ tau,
                                                  unsigned int* __restrict__ cnt) {
  __shared__ u64_t keys[NCHB_];
  int row = blockIdx.x, t = threadIdx.x;
  int k = *topk; if (k > 64) k = 64; if (k < 1) k = 1;
  for (int i = t; i < NCHB_; i += 256) keys[i] = chm[(size_t)row * NCHB_ + i];
  __syncthreads();
  u64_t mine[7]; int rank[7] = {0, 0, 0, 0, 0, 0, 0};
  #pragma unroll
  for (int o = 0; o < 7; ++o) {
    int i = o * 256 + t;
    mine[o] = (i < NCHB_) ? keys[i] : 0ull;
  }
  for (int j = 0; j < NCHB_; ++j) {
    u64_t kj = keys[j];
    #pragma unroll
    for (int o = 0; o < 7; ++o) rank[o] += (kj > mine[o]) ? 1 : 0;
  }
  #pragma unroll
  for (int o = 0; o < 7; ++o) {
    int i = o * 256 + t;
    if (i < NCHB_ && rank[o] == k - 1) tau[row] = mine[o];
  }
  if (t == 0) cnt[row] = 0u;
}

// ---------------- collect with chm-skip: scan ONLY chunks whose max >= tau ----------------
__global__ __launch_bounds__(256) void collect_kernel(const float* __restrict__ sims,
                                                      const u64_t* __restrict__ chm,
                                                      const u64_t* __restrict__ tau,
                                                      u64_t* __restrict__ cand,
                                                      unsigned int* __restrict__ cnt) {
  int id = blockIdx.x * 256 + threadIdx.x;
  if (id >= B_ * NCHB_) return;
  int row = id / NCHB_, c = id - row * NCHB_;
  u64_t tv = tau[row];
  if (chm[(size_t)row * NCHB_ + c] < tv) return;
  int base = c * 128;
  int end = base + 128; if (end > MEM_) end = MEM_;
  const float* src = sims + (size_t)row * MEM_;
  for (int i = base; i < end; ++i) {
    u64_t key = ((u64_t)f2key(src[i]) << 32) | (unsigned int)~(unsigned int)i;
    if (key >= tv) {
      unsigned int pos = atomicAdd(&cnt[row], 1u);
      if (pos < CAP_) cand[(size_t)row * CAP_ + pos] = key;
    }
  }
}

// ---------------- tail: final top-k + retrieve + gate/classifier (fused) ----------------
__global__ __launch_bounds__(256) void tail_kernel(const u64_t* __restrict__ cand,
                                                   const unsigned int* __restrict__ cnt,
                                                   const int* __restrict__ topk,
                                                   const float* __restrict__ vals,
                                                   const float* __restrict__ conf,
                                                   const float* __restrict__ pooled,
                                                   const float* __restrict__ gw1,
                                                   const float* __restrict__ gb1,
                                                   const float* __restrict__ gw2,
                                                   const float* __restrict__ gb2,
                                                   const float* __restrict__ cw,
                                                   const float* __restrict__ cb,
                                                   float* __restrict__ out) {
  __shared__ u64_t buf[CAP_];
  __shared__ u64_t wk[4];
  __shared__ float tv[64];
  __shared__ int ti[64];
  __shared__ float pl[D_], hh[D_], fu[D_], sh[8];
  int b = blockIdx.x, t = threadIdx.x;
  int k = *topk; if (k > 64) k = 64; if (k < 1) k = 1;
  int n = (int)cnt[b]; if (n > CAP_) n = CAP_;
  for (int i = t; i < n; i += 256) buf[i] = cand[(size_t)b * CAP_ + i];
  __syncthreads();
  int lane = t & 63, w = t >> 6;
  for (int iter = 0; iter < k; ++iter) {
    u64_t best = 0ull;
    for (int i = t; i < n; i += 256) best = ullmax(best, buf[i]);
    #pragma unroll
    for (int o = 32; o; o >>= 1) best = ullmax(best, __shfl_down(best, o));
    if (lane == 0) wk[w] = best;
    __syncthreads();
    best = ullmax(ullmax(wk[0], wk[1]), ullmax(wk[2], wk[3]));
    if (t == 0) {
      tv[iter] = key2f((unsigned int)(best >> 32));
      ti[iter] = (int)~(unsigned int)best;
    }
    for (int i = t; i < n; i += 256) if (buf[i] == best) buf[i] = 0ull;
    __syncthreads();
  }
  int d = t;
  float acc = 0.0f, wsum = 0.0f;
  for (int i = 0; i < k; ++i) {
    int idx = ti[i];
    float wgt = fmaxf(conf[idx], 1e-4f) * tv[i];
    wsum += wgt;
    acc += wgt * vals[(size_t)idx * D_ + d];
  }
  float retr = acc / (wsum + 1e-8f);
  pl[d] = pooled[b * D_ + d];
  __syncthreads();
  float a = gb1[d];
  for (int e = 0; e < D_; ++e) a += pl[e] * gw1[e * D_ + d];
  hh[d] = fmaxf(a, 0.0f);
  float gsum = blockReduceSum256(hh[d] * gw2[d], sh);
  float g = 1.0f / (1.0f + expf(-(gsum + gb2[0])));
  fu[d] = g * retr + (1.0f - g) * pl[d];
  __syncthreads();
  if (d < 16) {
    float o = cb[d];
    for (int e = 0; e < D_; ++e) o += fu[e] * cw[e * 16 + d];
    out[b * 16 + d] = o;
  }
}

// ---------------- launcher ----------------
extern "C" void kernel_launch(void* const* d_in, const int* in_sizes, int n_in,
                              void* d_out, int out_size, void* d_ws, size_t ws_size,
                              hipStream_t stream) {
  const int*   ids   = (const int*)d_in[0];
  const float* mask  = (const float*)d_in[1];
  const int*   topk  = (const int*)d_in[2];
  const float* emb   = (const float*)d_in[3];
  const float* qkv_w = (const float*)d_in[4];
  const float* qkv_b = (const float*)d_in[5];
  const float* out_w = (const float*)d_in[6];
  const float* out_b = (const float*)d_in[7];
  const float* ln1_s = (const float*)d_in[8];
  const float* ln1_b = (const float*)d_in[9];
  const float* ff_w1 = (const float*)d_in[10];
  const float* ff_b1 = (const float*)d_in[11];
  const float* ff_w2 = (const float*)d_in[12];
  const float* ff_b2 = (const float*)d_in[13];
  const float* ln2_s = (const float*)d_in[14];
  const float* ln2_b = (const float*)d_in[15];
  const float* lnf_s = (const float*)d_in[16];
  const float* lnf_b = (const float*)d_in[17];
  const float* gw1   = (const float*)d_in[18];
  const float* gb1   = (const float*)d_in[19];
  const float* gw2   = (const float*)d_in[20];
  const float* gb2   = (const float*)d_in[21];
  const float* cw    = (const float*)d_in[22];
  const float* cb    = (const float*)d_in[23];
  const float* mkeys = (const float*)d_in[24];
  const float* mvals = (const float*)d_in[25];
  const float* mconf = (const float*)d_in[26];
  float* out = (float*)d_out;

  // ---- workspace layout ----
  float* ws   = (float*)d_ws;
  float* X    = ws;                                   //  4,194,304 f
  float* Y    = X + 4194304;                          //  4,194,304 f
  float* R    = Y + 4194304;                          // 16,777,216 f
  ushort_t* XH   = (ushort_t*)(R + 16777216);
  ushort_t* XL   = XH + 4194304;
  ushort_t* CTXH = XL + 4194304;
  ushort_t* CTXL = CTXH + 4194304;
  ushort_t* WP   = CTXL + 4194304;                    //  3,145,728 sh
  float* POOL = (float*)(WP + 3145728);               //  16384 f
  ushort_t* QNH = (ushort_t*)(POOL + 16384);          //  16384 sh
  ushort_t* QNL = QNH + 16384;                        //  16384 sh
  u64_t* CANDK = (u64_t*)(QNL + 16384);               //  64*2048 u64
  u64_t* CHM   = CANDK + (size_t)B_ * CAP_;           //  64*1563 u64
  u64_t* TAU   = CHM + (size_t)B_ * NCHB_;            //  64 u64
  unsigned int* CNT = (unsigned int*)(TAU + B_);      //  64 u32

  // aliases over R (lifetimes disjoint)
  float*    QKVOUT = R;                  // [16384][768] f32
  ushort_t* BIGH   = (ushort_t*)R;       // [16384][1024] bf16 hi
  ushort_t* BIGL   = BIGH + 16777216;    // [16384][1024] bf16 lo
  float*    SIMS   = R;                  // [64][200000] f32

  const size_t LW = 1572864;
  #define WPTR(l, off) (WP + (size_t)(l) * LW + (off))

  transcvt_all<<<1536, 256, 0, stream>>>(qkv_w, out_w, ff_w1, ff_w2, WP);
  embed_kernel<<<ROWS_, 256, 0, stream>>>(ids, emb, X, XH, XL);

  for (int l = 0; l < 2; ++l) {
    gemm16<0, true, 0><<<dim3(6, 128), 256, 0, stream>>>(
        XH, XL, WPTR(l, 0), WPTR(l, 196608), qkv_b + l * 768,
        QKVOUT, nullptr, nullptr, ROWS_, 768, 256);
    attn_kernel<<<B_ * H_, 256, 0, stream>>>(QKVOUT, CTXH, CTXL);
    gemm16<0, true, 0><<<dim3(2, 128), 256, 0, stream>>>(
        CTXH, CTXL, WPTR(l, 393216), WPTR(l, 458752), out_b + l * 256,
        Y, nullptr, nullptr, ROWS_, 256, 256);
    addln_kernel<true><<<ROWS_, 256, 0, stream>>>(X, Y, ln1_s + l * 256, ln1_b + l * 256,
                                                  X, XH, XL);
    gemm16<1, true, 1><<<dim3(8, 128), 256, 0, stream>>>(
        XH, XL, WPTR(l, 524288), WPTR(l, 786432), ff_b1 + l * 1024,
        nullptr, BIGH, BIGL, ROWS_, 1024, 256);
    gemm16<0, true, 0><<<dim3(2, 128), 256, 0, stream>>>(
        BIGH, BIGL, WPTR(l, 1048576), WPTR(l, 1310720), ff_b2 + l * 256,
        Y, nullptr, nullptr, ROWS_, 256, 1024);
    addln_kernel<true><<<ROWS_, 256, 0, stream>>>(X, Y, ln2_s + l * 256, ln2_b + l * 256,
                                                  X, XH, XL);
  }

  addln_kernel<false><<<ROWS_, 256, 0, stream>>>(X, nullptr, lnf_s, lnf_b, Y, nullptr, nullptr);
  pooledqnorm_kernel<<<B_, 256, 0, stream>>>(Y, mask, POOL, QNH, QNL);
  sims_gemm<<<NCHB_, 256, 0, stream>>>(QNH, QNL, mkeys, SIMS, CHM);
  tau_kernel<<<B_, 256, 0, stream>>>(CHM, topk, TAU, CNT);
  collect_kernel<<<(B_ * NCHB_ + 255) / 256, 256, 0, stream>>>(SIMS, CHM, TAU, CANDK, CNT);
  tail_kernel<<<B_, 256, 0, stream>>>(CANDK, CNT, topk, mvals, mconf, POOL,
                                      gw1, gb1, gw2, gb2, cw, cb, out);
  #undef WPTR
}

// Round 14
// 714.373 us; speedup vs baseline: 1.0576x; 1.0576x over previous
//
#include <hip/hip_runtime.h>
#include <math.h>

// ---------------- constants ----------------
#define B_   64
#define S_   256
#define D_   256
#define H_   8
#define DH_  32
#define FF_  1024
#define MEM_ 200000
#define ROWS_ (B_ * S_)   // 16384
#define NCHB_ 1563        // sims blocks per row = chunk-max slots (ceil(MEM/128))
#define CAP_  2048        // candidate cap per row

typedef float f32x4 __attribute__((ext_vector_type(4)));
typedef __bf16 bf16x8 __attribute__((ext_vector_type(8)));
typedef unsigned short ushort_t;
typedef unsigned long long u64_t;

// ---------------- helpers ----------------
__device__ __forceinline__ float blockReduceSum256(float v, float* sh) {
  #pragma unroll
  for (int o = 32; o; o >>= 1) v += __shfl_down(v, o);
  int lane = threadIdx.x & 63, w = threadIdx.x >> 6;
  __syncthreads();
  if (lane == 0) sh[w] = v;
  __syncthreads();
  return sh[0] + sh[1] + sh[2] + sh[3];
}

__device__ __forceinline__ unsigned int f2key(float f) {
  unsigned int b = __float_as_uint(f);
  return (b & 0x80000000u) ? ~b : (b | 0x80000000u);
}
__device__ __forceinline__ float key2f(unsigned int u) {
  unsigned int b = (u & 0x80000000u) ? (u & 0x7FFFFFFFu) : ~u;
  return __uint_as_float(b);
}
__device__ __forceinline__ u64_t ullmax(u64_t a, u64_t b) { return a > b ? a : b; }

__device__ __forceinline__ ushort_t f32_bf16_rn(float x) {
  unsigned int u = __float_as_uint(x);
  u += 0x7FFFu + ((u >> 16) & 1u);
  return (ushort_t)(u >> 16);
}
__device__ __forceinline__ float bf16_f32(ushort_t h) {
  return __uint_as_float((unsigned int)h << 16);
}
__device__ __forceinline__ void split_bf16(float v, ushort_t& h, ushort_t& l) {
  h = f32_bf16_rn(v);
  l = f32_bf16_rn(v - bf16_f32(h));
}

// swizzled byte offset into a [R][32] bf16 LDS tile (16B granules, granule ^= (row>>1)&3)
__device__ __forceinline__ int swz16(int row, int kg) {
  return row * 64 + (((kg ^ ((row >> 1) & 3)) << 4));
}

// direct global->LDS 16B copy
__device__ __forceinline__ void gload_lds16(const void* gsrc, void* ldst) {
  __builtin_amdgcn_global_load_lds(
      (const __attribute__((address_space(1))) unsigned int*)gsrc,
      (__attribute__((address_space(3))) unsigned int*)(unsigned int)(unsigned long long)ldst,
      16, 0, 0);
}

// stage a [NIT*64 x 32] bf16 tile from linear global into swizzled LDS (pre-swizzled source)
template<int NIT>
__device__ __forceinline__ void stage16(const ushort_t* __restrict__ G, int ldg,
                                        int base_row, int k0, char* lds, int t) {
  #pragma unroll
  for (int r = 0; r < NIT; ++r) {
    int idx = r * 256 + t;
    int row = idx >> 2, kg = idx & 3;
    int kg_g = kg ^ ((row >> 1) & 3);
    const void* src = G + (size_t)(base_row + row) * ldg + k0 + kg_g * 8;
    void* dst = lds + (size_t)(idx & ~63) * 16;
    gload_lds16(src, dst);
  }
}

// ---------------- bf16x3 MFMA GEMM, 128x128 tile (round-8 form, all-LDS) ----------------
template<int ACT, bool HAS_BIAS, int OUTMODE>
__global__ __launch_bounds__(256) void gemm16(const ushort_t* __restrict__ AH,
                                              const ushort_t* __restrict__ AL,
                                              const ushort_t* __restrict__ BH,
                                              const ushort_t* __restrict__ BL,
                                              const float* __restrict__ bias,
                                              float* __restrict__ C,
                                              ushort_t* __restrict__ CH,
                                              ushort_t* __restrict__ CL,
                                              int M, int N, int K) {
  __shared__ __align__(16) char sAh[128 * 64];
  __shared__ __align__(16) char sAl[128 * 64];
  __shared__ __align__(16) char sBh[128 * 64];
  __shared__ __align__(16) char sBl[128 * 64];
  int t = threadIdx.x;
  int m0 = blockIdx.y * 128, n0 = blockIdx.x * 128;
  int wid = t >> 6, lane = t & 63;
  int wr = wid >> 1, wc = wid & 1;
  int lr = lane & 15, kg = lane >> 4;
  f32x4 acc[4][4] = {};
  for (int k0 = 0; k0 < K; k0 += 32) {
    stage16<2>(AH, K, m0, k0, sAh, t);
    stage16<2>(AL, K, m0, k0, sAl, t);
    stage16<2>(BH, K, n0, k0, sBh, t);
    stage16<2>(BL, K, n0, k0, sBl, t);
    __syncthreads();
    bf16x8 ah[4], al[4];
    #pragma unroll
    for (int mi = 0; mi < 4; ++mi) {
      int row = wr * 64 + mi * 16 + lr;
      int ab = swz16(row, kg);
      ah[mi] = *reinterpret_cast<const bf16x8*>(sAh + ab);
      al[mi] = *reinterpret_cast<const bf16x8*>(sAl + ab);
    }
    #pragma unroll
    for (int ni = 0; ni < 4; ++ni) {
      int rb = wc * 64 + ni * 16 + lr;
      int bb = swz16(rb, kg);
      bf16x8 bh = *reinterpret_cast<const bf16x8*>(sBh + bb);
      bf16x8 bl = *reinterpret_cast<const bf16x8*>(sBl + bb);
      #pragma unroll
      for (int mi = 0; mi < 4; ++mi) {
        acc[mi][ni] = __builtin_amdgcn_mfma_f32_16x16x32_bf16(ah[mi], bh, acc[mi][ni], 0, 0, 0);
        acc[mi][ni] = __builtin_amdgcn_mfma_f32_16x16x32_bf16(al[mi], bh, acc[mi][ni], 0, 0, 0);
        acc[mi][ni] = __builtin_amdgcn_mfma_f32_16x16x32_bf16(ah[mi], bl, acc[mi][ni], 0, 0, 0);
      }
    }
    __syncthreads();
  }
  #pragma unroll
  for (int mi = 0; mi < 4; ++mi) {
    #pragma unroll
    for (int ni = 0; ni < 4; ++ni) {
      int row0 = m0 + wr * 64 + mi * 16 + kg * 4;
      int col  = n0 + wc * 64 + ni * 16 + lr;
      float b = HAS_BIAS ? bias[col] : 0.0f;
      #pragma unroll
      for (int i = 0; i < 4; ++i) {
        float v = acc[mi][ni][i] + b;
        if (ACT == 1) v = 0.5f * v * (1.0f + erff(v * 0.7071067811865476f));
        size_t o = (size_t)(row0 + i) * N + col;
        if (OUTMODE == 0) {
          C[o] = v;
        } else {
          ushort_t h, l;
          split_bf16(v, h, l);
          CH[o] = h; CL[o] = l;
        }
      }
    }
  }
}

// ---------------- bf16x3 MFMA GEMM, 64x128 tile: for low-block-count (N=256) GEMMs ----------------
// 4 waves each own a 32x64 sub-tile (wr in {0,1} x wc in {0,1}), acc[2][4]. Same
// staging/swizzle idioms and K-accumulation order as gemm16 -> bit-identical results.
// Doubles grid to 512 blocks (2/CU, 2 waves/SIMD) for latency hiding.
template<int ACT, bool HAS_BIAS, int OUTMODE>
__global__ __launch_bounds__(256) void gemm16_64(const ushort_t* __restrict__ AH,
                                                 const ushort_t* __restrict__ AL,
                                                 const ushort_t* __restrict__ BH,
                                                 const ushort_t* __restrict__ BL,
                                                 const float* __restrict__ bias,
                                                 float* __restrict__ C,
                                                 ushort_t* __restrict__ CH,
                                                 ushort_t* __restrict__ CL,
                                                 int M, int N, int K) {
  __shared__ __align__(16) char sAh[64 * 64];
  __shared__ __align__(16) char sAl[64 * 64];
  __shared__ __align__(16) char sBh[128 * 64];
  __shared__ __align__(16) char sBl[128 * 64];
  int t = threadIdx.x;
  int m0 = blockIdx.y * 64, n0 = blockIdx.x * 128;
  int wid = t >> 6, lane = t & 63;
  int wr = wid >> 1, wc = wid & 1;
  int lr = lane & 15, kg = lane >> 4;
  f32x4 acc[2][4] = {};
  for (int k0 = 0; k0 < K; k0 += 32) {
    stage16<1>(AH, K, m0, k0, sAh, t);
    stage16<1>(AL, K, m0, k0, sAl, t);
    stage16<2>(BH, K, n0, k0, sBh, t);
    stage16<2>(BL, K, n0, k0, sBl, t);
    __syncthreads();
    bf16x8 ah[2], al[2];
    #pragma unroll
    for (int mi = 0; mi < 2; ++mi) {
      int row = wr * 32 + mi * 16 + lr;
      int ab = swz16(row, kg);
      ah[mi] = *reinterpret_cast<const bf16x8*>(sAh + ab);
      al[mi] = *reinterpret_cast<const bf16x8*>(sAl + ab);
    }
    #pragma unroll
    for (int ni = 0; ni < 4; ++ni) {
      int rb = wc * 64 + ni * 16 + lr;
      int bb = swz16(rb, kg);
      bf16x8 bh = *reinterpret_cast<const bf16x8*>(sBh + bb);
      bf16x8 bl = *reinterpret_cast<const bf16x8*>(sBl + bb);
      #pragma unroll
      for (int mi = 0; mi < 2; ++mi) {
        acc[mi][ni] = __builtin_amdgcn_mfma_f32_16x16x32_bf16(ah[mi], bh, acc[mi][ni], 0, 0, 0);
        acc[mi][ni] = __builtin_amdgcn_mfma_f32_16x16x32_bf16(al[mi], bh, acc[mi][ni], 0, 0, 0);
        acc[mi][ni] = __builtin_amdgcn_mfma_f32_16x16x32_bf16(ah[mi], bl, acc[mi][ni], 0, 0, 0);
      }
    }
    __syncthreads();
  }
  #pragma unroll
  for (int mi = 0; mi < 2; ++mi) {
    #pragma unroll
    for (int ni = 0; ni < 4; ++ni) {
      int row0 = m0 + wr * 32 + mi * 16 + kg * 4;
      int col  = n0 + wc * 64 + ni * 16 + lr;
      float b = HAS_BIAS ? bias[col] : 0.0f;
      #pragma unroll
      for (int i = 0; i < 4; ++i) {
        float v = acc[mi][ni][i] + b;
        if (ACT == 1) v = 0.5f * v * (1.0f + erff(v * 0.7071067811865476f));
        size_t o = (size_t)(row0 + i) * N + col;
        if (OUTMODE == 0) {
          C[o] = v;
        } else {
          ushort_t h, l;
          split_bf16(v, h, l);
          CH[o] = h; CL[o] = l;
        }
      }
    }
  }
}

// ---------------- sims GEMM v5: zero-barrier K-loop + 1-deep B prefetch ----------------
#define SIMS_STEP(BA, BB, SS, NI)                                                          \
  {                                                                                        \
    float q[8] = {BA.x, BA.y, BA.z, BA.w, BB.x, BB.y, BB.z, BB.w};                         \
    union { bf16x8 v; ushort_t u[8]; } bh, bl;                                             \
    float s_ = 0.f;                                                                        \
    _Pragma("unroll")                                                                      \
    for (int j = 0; j < 8; ++j) {                                                          \
      split_bf16(q[j], bh.u[j], bl.u[j]);                                                  \
      s_ += q[j] * q[j];                                                                   \
    }                                                                                      \
    SS += s_;                                                                              \
    _Pragma("unroll")                                                                      \
    for (int mi = 0; mi < 4; ++mi) {                                                       \
      acc[mi][NI] = __builtin_amdgcn_mfma_f32_16x16x32_bf16(ah[mi], bh.v, acc[mi][NI], 0, 0, 0); \
      acc[mi][NI] = __builtin_amdgcn_mfma_f32_16x16x32_bf16(al[mi], bh.v, acc[mi][NI], 0, 0, 0); \
      acc[mi][NI] = __builtin_amdgcn_mfma_f32_16x16x32_bf16(ah[mi], bl.v, acc[mi][NI], 0, 0, 0); \
    }                                                                                      \
  }

__global__ __launch_bounds__(256) void sims_gemm(const ushort_t* __restrict__ QNH,
                                                 const ushort_t* __restrict__ QNL,
                                                 const float* __restrict__ keys,
                                                 float* __restrict__ sims,
                                                 u64_t* __restrict__ chm) {
  __shared__ u64_t wmax[4][64];
  int t = threadIdx.x;
  int n0 = blockIdx.x * 128;
  int w = t >> 6, lane = t & 63;
  int lr = lane & 15, kg = lane >> 4;
  int col0 = n0 + w * 32 + lr;
  int col1 = col0 + 16;
  int c0 = col0 < MEM_ ? col0 : MEM_ - 1;
  int c1 = col1 < MEM_ ? col1 : MEM_ - 1;
  const float* kp0 = keys + (size_t)c0 * 256 + kg * 8;
  const float* kp1 = keys + (size_t)c1 * 256 + kg * 8;
  float ss0 = 0.f, ss1 = 0.f;
  f32x4 acc[4][2] = {};
  float4 b0a = *reinterpret_cast<const float4*>(kp0);
  float4 b0b = *reinterpret_cast<const float4*>(kp0 + 4);
  float4 b1a = *reinterpret_cast<const float4*>(kp1);
  float4 b1b = *reinterpret_cast<const float4*>(kp1 + 4);
  #pragma unroll
  for (int ks = 0; ks < 8; ++ks) {
    int k0 = ks * 32;
    float4 n0a, n0b, n1a, n1b;
    if (ks < 7) {
      n0a = *reinterpret_cast<const float4*>(kp0 + k0 + 32);
      n0b = *reinterpret_cast<const float4*>(kp0 + k0 + 36);
      n1a = *reinterpret_cast<const float4*>(kp1 + k0 + 32);
      n1b = *reinterpret_cast<const float4*>(kp1 + k0 + 36);
    }
    bf16x8 ah[4], al[4];
    #pragma unroll
    for (int mi = 0; mi < 4; ++mi) {
      size_t ao = (size_t)(mi * 16 + lr) * 256 + k0 + kg * 8;
      ah[mi] = *reinterpret_cast<const bf16x8*>(QNH + ao);
      al[mi] = *reinterpret_cast<const bf16x8*>(QNL + ao);
    }
    SIMS_STEP(b0a, b0b, ss0, 0)
    SIMS_STEP(b1a, b1b, ss1, 1)
    if (ks < 7) { b0a = n0a; b0b = n0b; b1a = n1a; b1b = n1b; }
  }
  float invn[2];
  {
    float s0 = ss0, s1 = ss1;
    s0 += __shfl_xor(s0, 16); s0 += __shfl_xor(s0, 32);
    s1 += __shfl_xor(s1, 16); s1 += __shfl_xor(s1, 32);
    invn[0] = 1.0f / fmaxf(sqrtf(s0), 1e-8f);
    invn[1] = 1.0f / fmaxf(sqrtf(s1), 1e-8f);
  }
  u64_t bq[4][4];
  #pragma unroll
  for (int mi = 0; mi < 4; ++mi)
    #pragma unroll
    for (int i = 0; i < 4; ++i) bq[mi][i] = 0ull;
  #pragma unroll
  for (int ni = 0; ni < 2; ++ni) {
    int col = ni ? col1 : col0;
    if (col < MEM_) {
      #pragma unroll
      for (int mi = 0; mi < 4; ++mi) {
        int q = mi * 16 + kg * 4;
        #pragma unroll
        for (int i = 0; i < 4; ++i) {
          float v = acc[mi][ni][i] * invn[ni];
          sims[(size_t)(q + i) * MEM_ + col] = v;
          u64_t key = ((u64_t)f2key(v) << 32) | (unsigned int)~(unsigned int)col;
          bq[mi][i] = ullmax(bq[mi][i], key);
        }
      }
    }
  }
  #pragma unroll
  for (int mi = 0; mi < 4; ++mi)
    #pragma unroll
    for (int i = 0; i < 4; ++i) {
      u64_t m = bq[mi][i];
      m = ullmax(m, __shfl_xor(m, 1));
      m = ullmax(m, __shfl_xor(m, 2));
      m = ullmax(m, __shfl_xor(m, 4));
      m = ullmax(m, __shfl_xor(m, 8));
      if (lr == 0) wmax[w][mi * 16 + kg * 4 + i] = m;
    }
  __syncthreads();
  if (t < 64) {
    u64_t m = ullmax(ullmax(wmax[0][t], wmax[1][t]), ullmax(wmax[2][t], wmax[3][t]));
    chm[(size_t)t * NCHB_ + blockIdx.x] = m;
  }
}

// ---------------- all weight transposes + bf16 hi/lo split in ONE launch ----------------
__global__ __launch_bounds__(256) void transcvt_all(const float* __restrict__ qkv_w,
                                                    const float* __restrict__ out_w,
                                                    const float* __restrict__ ff_w1,
                                                    const float* __restrict__ ff_w2,
                                                    ushort_t* __restrict__ WP) {
  __shared__ float tile[32][33];
  int idx = blockIdx.x;
  int l = idx / 768, r = idx % 768;
  const float* src; ushort_t *dh, *dl; int R, C, bx, by;
  ushort_t* base = WP + (size_t)l * 1572864;
  if (r < 192)      { src = qkv_w + (size_t)l * 196608; dh = base;           dl = base + 196608;  R = 256;  C = 768;  bx = r % 24;        by = r / 24; }
  else if (r < 256) { src = out_w + (size_t)l * 65536;  dh = base + 393216;  dl = base + 458752;  R = 256;  C = 256;  bx = (r - 192) % 8; by = (r - 192) / 8; }
  else if (r < 512) { src = ff_w1 + (size_t)l * 262144; dh = base + 524288;  dl = base + 786432;  R = 256;  C = 1024; bx = (r - 256) % 32; by = (r - 256) / 32; }
  else              { src = ff_w2 + (size_t)l * 262144; dh = base + 1048576; dl = base + 1310720; R = 1024; C = 256;  bx = (r - 512) % 8; by = (r - 512) / 8; }
  int c0 = bx * 32, r0 = by * 32;
  int x = threadIdx.x & 31, y4 = (threadIdx.x >> 5) * 4;
  #pragma unroll
  for (int i = 0; i < 4; ++i) tile[y4 + i][x] = src[(size_t)(r0 + y4 + i) * C + c0 + x];
  __syncthreads();
  #pragma unroll
  for (int i = 0; i < 4; ++i) {
    float v = tile[x][y4 + i];
    ushort_t h, l2;
    split_bf16(v, h, l2);
    size_t o = (size_t)(c0 + y4 + i) * R + r0 + x;
    dh[o] = h; dl[o] = l2;
  }
}

// ---------------- embedding + positional encoding ----------------
__global__ __launch_bounds__(256) void embed_kernel(const int* __restrict__ ids,
                                                    const float* __restrict__ emb,
                                                    float* __restrict__ x,
                                                    ushort_t* __restrict__ xh,
                                                    ushort_t* __restrict__ xl) {
  int row = blockIdx.x;
  int d = threadIdx.x;
  int s = row & (S_ - 1);
  int tok = ids[row];
  int d2 = d & ~1;
  float div = expf((float)d2 * (-9.210340371976184f / 256.0f));
  float ang = (float)s * div;
  float pe = (d & 1) ? cosf(ang) : sinf(ang);
  float v = emb[(size_t)tok * D_ + d] * 16.0f + pe;
  size_t o = (size_t)row * D_ + d;
  x[o] = v;
  ushort_t h, l;
  split_bf16(v, h, l);
  xh[o] = h; xl[o] = l;
}

// ---------------- MFMA flash attention (round-8 form: f32 QKV in, LDS staging) ----------------
__global__ __launch_bounds__(256) void attn_kernel(const float* __restrict__ qkv,
                                                   ushort_t* __restrict__ ctxh,
                                                   ushort_t* __restrict__ ctxl) {
  __shared__ __align__(16) ushort_t sKh[32][40];
  __shared__ __align__(16) ushort_t sKl[32][40];
  __shared__ __align__(16) ushort_t sVh[32][40];
  __shared__ __align__(16) ushort_t sVl[32][40];
  __shared__ __align__(16) ushort_t sPh[4][64][40];
  __shared__ __align__(16) ushort_t sPl[4][64][40];

  const int bh = blockIdx.x;
  const int b = bh >> 3, h = bh & 7;
  const int t = threadIdx.x;
  const int w = t >> 6, lane = t & 63;
  const int lr = lane & 15, g = lane >> 4;

  const float* __restrict__ base = qkv + (size_t)(b * S_) * 768 + h * 32;

  bf16x8 qh[4], ql[4];
  #pragma unroll
  for (int ni = 0; ni < 4; ++ni) {
    const float* qp = base + (size_t)(w * 64 + ni * 16 + lr) * 768 + g * 8;
    union { bf16x8 v; ushort_t u[8]; } Hh, Ll;
    #pragma unroll
    for (int j = 0; j < 8; ++j) {
      float qv = qp[j] * 0.17677669529663687f;
      split_bf16(qv, Hh.u[j], Ll.u[j]);
    }
    qh[ni] = Hh.v; ql[ni] = Ll.v;
  }

  f32x4 oacc[2][4] = {};
  float mrow[4] = {-3.0e38f, -3.0e38f, -3.0e38f, -3.0e38f};
  float lsum[4] = {0.f, 0.f, 0.f, 0.f};

  for (int kt = 0; kt < 8; ++kt) {
    __syncthreads();
    {
      int key = t >> 3, c4 = t & 7;
      const float4 kv = *reinterpret_cast<const float4*>(
          base + (size_t)(kt * 32 + key) * 768 + 256 + c4 * 4);
      float kvv[4] = {kv.x, kv.y, kv.z, kv.w};
      ushort_t hk[4], lk[4];
      #pragma unroll
      for (int j = 0; j < 4; ++j) split_bf16(kvv[j], hk[j], lk[j]);
      *reinterpret_cast<uint2*>(&sKh[key][c4 * 4]) =
          make_uint2((unsigned)hk[0] | ((unsigned)hk[1] << 16),
                     (unsigned)hk[2] | ((unsigned)hk[3] << 16));
      *reinterpret_cast<uint2*>(&sKl[key][c4 * 4]) =
          make_uint2((unsigned)lk[0] | ((unsigned)lk[1] << 16),
                     (unsigned)lk[2] | ((unsigned)lk[3] << 16));
      int dh = t & 31, kq = t >> 5;
      ushort_t hv[4], lv[4];
      #pragma unroll
      for (int kk = 0; kk < 4; ++kk) {
        float vv = base[(size_t)(kt * 32 + kq * 4 + kk) * 768 + 512 + dh];
        split_bf16(vv, hv[kk], lv[kk]);
      }
      *reinterpret_cast<uint2*>(&sVh[dh][kq * 4]) =
          make_uint2((unsigned)hv[0] | ((unsigned)hv[1] << 16),
                     (unsigned)hv[2] | ((unsigned)hv[3] << 16));
      *reinterpret_cast<uint2*>(&sVl[dh][kq * 4]) =
          make_uint2((unsigned)lv[0] | ((unsigned)lv[1] << 16),
                     (unsigned)lv[2] | ((unsigned)lv[3] << 16));
    }
    __syncthreads();

    f32x4 sacc[2][4] = {};
    bf16x8 kfh[2], kfl[2];
    #pragma unroll
    for (int x = 0; x < 2; ++x) {
      kfh[x] = *reinterpret_cast<const bf16x8*>(&sKh[x * 16 + lr][g * 8]);
      kfl[x] = *reinterpret_cast<const bf16x8*>(&sKl[x * 16 + lr][g * 8]);
    }
    #pragma unroll
    for (int x = 0; x < 2; ++x) {
      #pragma unroll
      for (int ni = 0; ni < 4; ++ni) {
        sacc[x][ni] = __builtin_amdgcn_mfma_f32_16x16x32_bf16(kfh[x], qh[ni], sacc[x][ni], 0, 0, 0);
        sacc[x][ni] = __builtin_amdgcn_mfma_f32_16x16x32_bf16(kfl[x], qh[ni], sacc[x][ni], 0, 0, 0);
        sacc[x][ni] = __builtin_amdgcn_mfma_f32_16x16x32_bf16(kfh[x], ql[ni], sacc[x][ni], 0, 0, 0);
      }
    }

    #pragma unroll
    for (int ni = 0; ni < 4; ++ni) {
      float tm = sacc[0][ni][0];
      tm = fmaxf(tm, sacc[0][ni][1]); tm = fmaxf(tm, sacc[0][ni][2]); tm = fmaxf(tm, sacc[0][ni][3]);
      tm = fmaxf(tm, sacc[1][ni][0]); tm = fmaxf(tm, sacc[1][ni][1]);
      tm = fmaxf(tm, sacc[1][ni][2]); tm = fmaxf(tm, sacc[1][ni][3]);
      tm = fmaxf(tm, __shfl_xor(tm, 16));
      tm = fmaxf(tm, __shfl_xor(tm, 32));
      float mn = fmaxf(mrow[ni], tm);
      float sc = __expf(mrow[ni] - mn);
      mrow[ni] = mn;
      float ps = 0.f;
      #pragma unroll
      for (int x = 0; x < 2; ++x) {
        ushort_t ph[4], pl[4];
        #pragma unroll
        for (int i = 0; i < 4; ++i) {
          float p = __expf(sacc[x][ni][i] - mn);
          ps += p;
          split_bf16(p, ph[i], pl[i]);
        }
        *reinterpret_cast<uint2*>(&sPh[w][ni * 16 + lr][x * 16 + g * 4]) =
            make_uint2((unsigned)ph[0] | ((unsigned)ph[1] << 16),
                       (unsigned)ph[2] | ((unsigned)ph[3] << 16));
        *reinterpret_cast<uint2*>(&sPl[w][ni * 16 + lr][x * 16 + g * 4]) =
            make_uint2((unsigned)pl[0] | ((unsigned)pl[1] << 16),
                       (unsigned)pl[2] | ((unsigned)pl[3] << 16));
      }
      ps += __shfl_xor(ps, 16);
      ps += __shfl_xor(ps, 32);
      lsum[ni] = lsum[ni] * sc + ps;
      #pragma unroll
      for (int mt = 0; mt < 2; ++mt)
        #pragma unroll
        for (int i = 0; i < 4; ++i) oacc[mt][ni][i] *= sc;
    }

    bf16x8 pbh[4], pbl[4];
    #pragma unroll
    for (int ni = 0; ni < 4; ++ni) {
      pbh[ni] = *reinterpret_cast<const bf16x8*>(&sPh[w][ni * 16 + lr][g * 8]);
      pbl[ni] = *reinterpret_cast<const bf16x8*>(&sPl[w][ni * 16 + lr][g * 8]);
    }
    #pragma unroll
    for (int mt = 0; mt < 2; ++mt) {
      bf16x8 vfh = *reinterpret_cast<const bf16x8*>(&sVh[mt * 16 + lr][g * 8]);
      bf16x8 vfl = *reinterpret_cast<const bf16x8*>(&sVl[mt * 16 + lr][g * 8]);
      #pragma unroll
      for (int ni = 0; ni < 4; ++ni) {
        oacc[mt][ni] = __builtin_amdgcn_mfma_f32_16x16x32_bf16(vfh, pbh[ni], oacc[mt][ni], 0, 0, 0);
        oacc[mt][ni] = __builtin_amdgcn_mfma_f32_16x16x32_bf16(vfl, pbh[ni], oacc[mt][ni], 0, 0, 0);
        oacc[mt][ni] = __builtin_amdgcn_mfma_f32_16x16x32_bf16(vfh, pbl[ni], oacc[mt][ni], 0, 0, 0);
      }
    }
  }

  #pragma unroll
  for (int ni = 0; ni < 4; ++ni) {
    float inv = 1.0f / lsum[ni];
    int q = w * 64 + ni * 16 + lr;
    size_t rowo = (size_t)(b * S_ + q) * D_ + h * 32;
    #pragma unroll
    for (int mt = 0; mt < 2; ++mt) {
      ushort_t hh[4], ll[4];
      #pragma unroll
      for (int i = 0; i < 4; ++i) {
        float v = oacc[mt][ni][i] * inv;
        split_bf16(v, hh[i], ll[i]);
      }
      int col = mt * 16 + g * 4;
      *reinterpret_cast<uint2*>(&ctxh[rowo + col]) =
          make_uint2((unsigned)hh[0] | ((unsigned)hh[1] << 16),
                     (unsigned)hh[2] | ((unsigned)hh[3] << 16));
      *reinterpret_cast<uint2*>(&ctxl[rowo + col]) =
          make_uint2((unsigned)ll[0] | ((unsigned)ll[1] << 16),
                     (unsigned)ll[2] | ((unsigned)ll[3] << 16));
    }
  }
}

// ---------------- residual add + layernorm ----------------
template<bool PAIRS>
__global__ __launch_bounds__(256) void addln_kernel(const float* __restrict__ x,
                                                    const float* __restrict__ y,
                                                    const float* __restrict__ gam,
                                                    const float* __restrict__ bet,
                                                    float* __restrict__ out,
                                                    ushort_t* __restrict__ oh,
                                                    ushort_t* __restrict__ ol) {
  __shared__ float sh[8];
  int row = blockIdx.x, d = threadIdx.x;
  float v = x[(size_t)row * D_ + d];
  if (y) v += y[(size_t)row * D_ + d];
  float mean = blockReduceSum256(v, sh) * (1.0f / D_);
  float diff = v - mean;
  float var = blockReduceSum256(diff * diff, sh) * (1.0f / D_);
  float r = diff * rsqrtf(var + 1e-5f) * gam[d] + bet[d];
  size_t o = (size_t)row * D_ + d;
  out[o] = r;
  if (PAIRS) {
    ushort_t h, l;
    split_bf16(r, h, l);
    oh[o] = h; ol[o] = l;
  }
}

// ---------------- masked mean pool + query normalize (fused; bf16-pair qn out) ----------------
__global__ __launch_bounds__(256) void pooledqnorm_kernel(const float* __restrict__ hidden,
                                                          const float* __restrict__ mask,
                                                          float* __restrict__ pooled,
                                                          ushort_t* __restrict__ qnh,
                                                          ushort_t* __restrict__ qnl) {
  __shared__ float sh[8];
  int b = blockIdx.x, d = threadIdx.x;
  float s = 0.0f, msum = 0.0f;
  for (int t = 0; t < S_; ++t) {
    float mk = mask[b * S_ + t];
    s += hidden[(size_t)(b * S_ + t) * D_ + d] * mk;
    msum += mk;
  }
  float pv = s / (msum + 1e-8f);
  pooled[b * D_ + d] = pv;
  float ss = blockReduceSum256(pv * pv, sh);
  float qv = pv / fmaxf(sqrtf(ss), 1e-8f);
  ushort_t h, l;
  split_bf16(qv, h, l);
  qnh[b * D_ + d] = h;
  qnl[b * D_ + d] = l;
}

// ---------------- tau: k-th largest of 1563 chunk maxima per row ----------------
__global__ __launch_bounds__(256) void tau_kernel(const u64_t* __restrict__ chm,
                                                  const int* __restrict__ topk,
                                                  u64_t* __restrict__ tau,
                                                  unsigned int* __restrict__ cnt) {
  __shared__ u64_t keys[NCHB_];
  int row = blockIdx.x, t = threadIdx.x;
  int k = *topk; if (k > 64) k = 64; if (k < 1) k = 1;
  for (int i = t; i < NCHB_; i += 256) keys[i] = chm[(size_t)row * NCHB_ + i];
  __syncthreads();
  u64_t mine[7]; int rank[7] = {0, 0, 0, 0, 0, 0, 0};
  #pragma unroll
  for (int o = 0; o < 7; ++o) {
    int i = o * 256 + t;
    mine[o] = (i < NCHB_) ? keys[i] : 0ull;
  }
  for (int j = 0; j < NCHB_; ++j) {
    u64_t kj = keys[j];
    #pragma unroll
    for (int o = 0; o < 7; ++o) rank[o] += (kj > mine[o]) ? 1 : 0;
  }
  #pragma unroll
  for (int o = 0; o < 7; ++o) {
    int i = o * 256 + t;
    if (i < NCHB_ && rank[o] == k - 1) tau[row] = mine[o];
  }
  if (t == 0) cnt[row] = 0u;
}

// ---------------- collect with chm-skip: scan ONLY chunks whose max >= tau ----------------
__global__ __launch_bounds__(256) void collect_kernel(const float* __restrict__ sims,
                                                      const u64_t* __restrict__ chm,
                                                      const u64_t* __restrict__ tau,
                                                      u64_t* __restrict__ cand,
                                                      unsigned int* __restrict__ cnt) {
  int id = blockIdx.x * 256 + threadIdx.x;
  if (id >= B_ * NCHB_) return;
  int row = id / NCHB_, c = id - row * NCHB_;
  u64_t tv = tau[row];
  if (chm[(size_t)row * NCHB_ + c] < tv) return;
  int base = c * 128;
  int end = base + 128; if (end > MEM_) end = MEM_;
  const float* src = sims + (size_t)row * MEM_;
  for (int i = base; i < end; ++i) {
    u64_t key = ((u64_t)f2key(src[i]) << 32) | (unsigned int)~(unsigned int)i;
    if (key >= tv) {
      unsigned int pos = atomicAdd(&cnt[row], 1u);
      if (pos < CAP_) cand[(size_t)row * CAP_ + pos] = key;
    }
  }
}

// ---------------- tail: final top-k + retrieve + gate/classifier (fused) ----------------
__global__ __launch_bounds__(256) void tail_kernel(const u64_t* __restrict__ cand,
                                                   const unsigned int* __restrict__ cnt,
                                                   const int* __restrict__ topk,
                                                   const float* __restrict__ vals,
                                                   const float* __restrict__ conf,
                                                   const float* __restrict__ pooled,
                                                   const float* __restrict__ gw1,
                                                   const float* __restrict__ gb1,
                                                   const float* __restrict__ gw2,
                                                   const float* __restrict__ gb2,
                                                   const float* __restrict__ cw,
                                                   const float* __restrict__ cb,
                                                   float* __restrict__ out) {
  __shared__ u64_t buf[CAP_];
  __shared__ u64_t wk[4];
  __shared__ float tv[64];
  __shared__ int ti[64];
  __shared__ float pl[D_], hh[D_], fu[D_], sh[8];
  int b = blockIdx.x, t = threadIdx.x;
  int k = *topk; if (k > 64) k = 64; if (k < 1) k = 1;
  int n = (int)cnt[b]; if (n > CAP_) n = CAP_;
  for (int i = t; i < n; i += 256) buf[i] = cand[(size_t)b * CAP_ + i];
  __syncthreads();
  int lane = t & 63, w = t >> 6;
  for (int iter = 0; iter < k; ++iter) {
    u64_t best = 0ull;
    for (int i = t; i < n; i += 256) best = ullmax(best, buf[i]);
    #pragma unroll
    for (int o = 32; o; o >>= 1) best = ullmax(best, __shfl_down(best, o));
    if (lane == 0) wk[w] = best;
    __syncthreads();
    best = ullmax(ullmax(wk[0], wk[1]), ullmax(wk[2], wk[3]));
    if (t == 0) {
      tv[iter] = key2f((unsigned int)(best >> 32));
      ti[iter] = (int)~(unsigned int)best;
    }
    for (int i = t; i < n; i += 256) if (buf[i] == best) buf[i] = 0ull;
    __syncthreads();
  }
  int d = t;
  float acc = 0.0f, wsum = 0.0f;
  for (int i = 0; i < k; ++i) {
    int idx = ti[i];
    float wgt = fmaxf(conf[idx], 1e-4f) * tv[i];
    wsum += wgt;
    acc += wgt * vals[(size_t)idx * D_ + d];
  }
  float retr = acc / (wsum + 1e-8f);
  pl[d] = pooled[b * D_ + d];
  __syncthreads();
  float a = gb1[d];
  for (int e = 0; e < D_; ++e) a += pl[e] * gw1[e * D_ + d];
  hh[d] = fmaxf(a, 0.0f);
  float gsum = blockReduceSum256(hh[d] * gw2[d], sh);
  float g = 1.0f / (1.0f + expf(-(gsum + gb2[0])));
  fu[d] = g * retr + (1.0f - g) * pl[d];
  __syncthreads();
  if (d < 16) {
    float o = cb[d];
    for (int e = 0; e < D_; ++e) o += fu[e] * cw[e * 16 + d];
    out[b * 16 + d] = o;
  }
}

// ---------------- launcher ----------------
extern "C" void kernel_launch(void* const* d_in, const int* in_sizes, int n_in,
                              void* d_out, int out_size, void* d_ws, size_t ws_size,
                              hipStream_t stream) {
  const int*   ids   = (const int*)d_in[0];
  const float* mask  = (const float*)d_in[1];
  const int*   topk  = (const int*)d_in[2];
  const float* emb   = (const float*)d_in[3];
  const float* qkv_w = (const float*)d_in[4];
  const float* qkv_b = (const float*)d_in[5];
  const float* out_w = (const float*)d_in[6];
  const float* out_b = (const float*)d_in[7];
  const float* ln1_s = (const float*)d_in[8];
  const float* ln1_b = (const float*)d_in[9];
  const float* ff_w1 = (const float*)d_in[10];
  const float* ff_b1 = (const float*)d_in[11];
  const float* ff_w2 = (const float*)d_in[12];
  const float* ff_b2 = (const float*)d_in[13];
  const float* ln2_s = (const float*)d_in[14];
  const float* ln2_b = (const float*)d_in[15];
  const float* lnf_s = (const float*)d_in[16];
  const float* lnf_b = (const float*)d_in[17];
  const float* gw1   = (const float*)d_in[18];
  const float* gb1   = (const float*)d_in[19];
  const float* gw2   = (const float*)d_in[20];
  const float* gb2   = (const float*)d_in[21];
  const float* cw    = (const float*)d_in[22];
  const float* cb    = (const float*)d_in[23];
  const float* mkeys = (const float*)d_in[24];
  const float* mvals = (const float*)d_in[25];
  const float* mconf = (const float*)d_in[26];
  float* out = (float*)d_out;

  // ---- workspace layout ----
  float* ws   = (float*)d_ws;
  float* X    = ws;                                   //  4,194,304 f
  float* Y    = X + 4194304;                          //  4,194,304 f
  float* R    = Y + 4194304;                          // 16,777,216 f
  ushort_t* XH   = (ushort_t*)(R + 16777216);
  ushort_t* XL   = XH + 4194304;
  ushort_t* CTXH = XL + 4194304;
  ushort_t* CTXL = CTXH + 4194304;
  ushort_t* WP   = CTXL + 4194304;                    //  3,145,728 sh
  float* POOL = (float*)(WP + 3145728);               //  16384 f
  ushort_t* QNH = (ushort_t*)(POOL + 16384);          //  16384 sh
  ushort_t* QNL = QNH + 16384;                        //  16384 sh
  u64_t* CANDK = (u64_t*)(QNL + 16384);               //  64*2048 u64
  u64_t* CHM   = CANDK + (size_t)B_ * CAP_;           //  64*1563 u64
  u64_t* TAU   = CHM + (size_t)B_ * NCHB_;            //  64 u64
  unsigned int* CNT = (unsigned int*)(TAU + B_);      //  64 u32

  // aliases over R (lifetimes disjoint)
  float*    QKVOUT = R;                  // [16384][768] f32
  ushort_t* BIGH   = (ushort_t*)R;       // [16384][1024] bf16 hi
  ushort_t* BIGL   = BIGH + 16777216;    // [16384][1024] bf16 lo
  float*    SIMS   = R;                  // [64][200000] f32

  const size_t LW = 1572864;
  #define WPTR(l, off) (WP + (size_t)(l) * LW + (off))

  transcvt_all<<<1536, 256, 0, stream>>>(qkv_w, out_w, ff_w1, ff_w2, WP);
  embed_kernel<<<ROWS_, 256, 0, stream>>>(ids, emb, X, XH, XL);

  for (int l = 0; l < 2; ++l) {
    gemm16<0, true, 0><<<dim3(6, 128), 256, 0, stream>>>(
        XH, XL, WPTR(l, 0), WPTR(l, 196608), qkv_b + l * 768,
        QKVOUT, nullptr, nullptr, ROWS_, 768, 256);
    attn_kernel<<<B_ * H_, 256, 0, stream>>>(QKVOUT, CTXH, CTXL);
    gemm16_64<0, true, 0><<<dim3(2, 256), 256, 0, stream>>>(
        CTXH, CTXL, WPTR(l, 393216), WPTR(l, 458752), out_b + l * 256,
        Y, nullptr, nullptr, ROWS_, 256, 256);
    addln_kernel<true><<<ROWS_, 256, 0, stream>>>(X, Y, ln1_s + l * 256, ln1_b + l * 256,
                                                  X, XH, XL);
    gemm16<1, true, 1><<<dim3(8, 128), 256, 0, stream>>>(
        XH, XL, WPTR(l, 524288), WPTR(l, 786432), ff_b1 + l * 1024,
        nullptr, BIGH, BIGL, ROWS_, 1024, 256);
    gemm16_64<0, true, 0><<<dim3(2, 256), 256, 0, stream>>>(
        BIGH, BIGL, WPTR(l, 1048576), WPTR(l, 1310720), ff_b2 + l * 256,
        Y, nullptr, nullptr, ROWS_, 256, 1024);
    addln_kernel<true><<<ROWS_, 256, 0, stream>>>(X, Y, ln2_s + l * 256, ln2_b + l * 256,
                                                  X, XH, XL);
  }

  addln_kernel<false><<<ROWS_, 256, 0, stream>>>(X, nullptr, lnf_s, lnf_b, Y, nullptr, nullptr);
  pooledqnorm_kernel<<<B_, 256, 0, stream>>>(Y, mask, POOL, QNH, QNL);
  sims_gemm<<<NCHB_, 256, 0, stream>>>(QNH, QNL, mkeys, SIMS, CHM);
  tau_kernel<<<B_, 256, 0, stream>>>(CHM, topk, TAU, CNT);
  collect_kernel<<<(B_ * NCHB_ + 255) / 256, 256, 0, stream>>>(SIMS, CHM, TAU, CANDK, CNT);
  tail_kernel<<<B_, 256, 0, stream>>>(CANDK, CNT, topk, mvals, mconf, POOL,
                                      gw1, gb1, gw2, gb2, cw, cb, out);
  #undef WPTR
}